// Round 4
// baseline (348.015 us; speedup 1.0000x reference)
//
#include <hip/hip_runtime.h>
#include <math.h>

#define OUTN  4096
#define CONVN 27
#define NPTS  (OUTN * CONVN)     // 110592
#define NQUAD (NPTS / 4)         // 27648 = 108 * 256 point-quads
#define NB    30
#define NOI   256                // OUTC * INC
#define OI_CHUNK 32              // oi per block
#define NCHUNK (NOI / OI_CHUNK)  // 8

// Evaluate the 30 hydrogen-wavefunction basis values for one point.
__device__ __forceinline__ void eval_basis(float r, float theta, float phi,
                                           float* __restrict__ bas)
{
    // ---- angular pieces ----
    const float ct = cosf(theta);
    const float st = sqrtf(fmaxf(1.0f - ct * ct, 0.0f));  // matches ref clip
    float s1, c1;
    sincosf(phi, &s1, &c1);
    const float c2 = c1 * c1 - s1 * s1;
    const float s2 = 2.0f * c1 * s1;
    const float c3 = c2 * c1 - s2 * s1;
    const float s3 = s2 * c1 + c2 * s1;

    // Associated Legendre with Condon–Shortley phase (matches ref _plm)
    const float P11 = -st;
    const float P20 = 0.5f * (3.0f * ct * ct - 1.0f);
    const float P21 = -3.0f * ct * st;
    const float P22 = 3.0f * (1.0f - ct * ct);
    const float P30 = 0.5f * ct * (5.0f * ct * ct - 3.0f);
    const float P31 = -1.5f * (5.0f * ct * ct - 1.0f) * st;
    const float P32 = 15.0f * ct * (1.0f - ct * ct);
    const float P33 = -15.0f * st * st * st;

    // Y_lm normalization constants (sqrtf of literals -> constant-folded)
    const float PI   = 3.14159265358979323846f;
    const float K00  = sqrtf(1.0f / (4.0f * PI));
    const float K10  = sqrtf(3.0f / (4.0f * PI));
    const float SK11 = sqrtf(2.0f) * sqrtf(3.0f / (8.0f * PI));
    const float K20  = sqrtf(5.0f / (4.0f * PI));
    const float SK21 = sqrtf(2.0f) * sqrtf(5.0f / (24.0f * PI));
    const float SK22 = sqrtf(2.0f) * sqrtf(5.0f / (96.0f * PI));
    const float K30  = sqrtf(7.0f / (4.0f * PI));
    const float SK31 = sqrtf(2.0f) * sqrtf(7.0f / (48.0f * PI));
    const float SK32 = sqrtf(2.0f) * sqrtf(7.0f / (480.0f * PI));
    const float SK33 = sqrtf(2.0f) * sqrtf(7.0f / (2880.0f * PI));

    const float Y00  = K00;
    const float Y1m1 = SK11 * P11 * s1;
    const float Y10  = K10 * ct;
    const float Y1p1 = SK11 * P11 * c1;
    const float Y2m2 = SK22 * P22 * s2;
    const float Y2m1 = SK21 * P21 * s1;
    const float Y20  = K20 * P20;
    const float Y2p1 = SK21 * P21 * c1;
    const float Y2p2 = SK22 * P22 * c2;
    const float Y3m3 = SK33 * P33 * s3;
    const float Y3m2 = SK32 * P32 * s2;
    const float Y3m1 = SK31 * P31 * s1;
    const float Y30  = K30 * P30;
    const float Y3p1 = SK31 * P31 * c1;
    const float Y3p2 = SK32 * P32 * c2;
    const float Y3p3 = SK33 * P33 * c3;

    // ---- radial parts R_nl(r), Bohr radius 1, rho = 2r/n ----
    const float e1 = expf(-r);                 // n=1
    const float e2 = expf(-0.5f * r);          // n=2
    const float e3 = expf(-r * (1.0f / 3.0f)); // n=3
    const float e4 = expf(-0.25f * r);         // n=4
    const float q2 = r;
    const float q3 = (2.0f / 3.0f) * r;
    const float q4 = 0.5f * r;

    const float R10 = 2.0f * e1;
    const float R20 = sqrtf(1.0f / 8.0f)       * e2 * (2.0f - q2);
    const float R21 = sqrtf(1.0f / 24.0f)      * e2 * q2;
    const float R30 = sqrtf(8.0f / 486.0f)     * e3 * (3.0f - 3.0f * q3 + 0.5f * q3 * q3);
    const float R31 = sqrtf(8.0f / 3888.0f)    * e3 * q3 * (4.0f - q3);
    const float R32 = sqrtf(8.0f / 19440.0f)   * e3 * q3 * q3;
    const float R40 = 0.0625f                  * e4 * (4.0f - 6.0f * q4 + 2.0f * q4 * q4 - q4 * q4 * q4 * (1.0f / 6.0f));
    const float R41 = sqrtf(0.25f / 960.0f)    * e4 * q4 * (10.0f - 5.0f * q4 + 0.5f * q4 * q4);
    const float R42 = sqrtf(0.125f / 5760.0f)  * e4 * q4 * q4 * (6.0f - q4);
    const float R43 = sqrtf(0.125f / 40320.0f) * e4 * q4 * q4 * q4;

    // ---- basis in QNUMS order ----
    bas[0]  = R10 * Y00;
    bas[1]  = R20 * Y00;
    bas[2]  = R21 * Y1m1;
    bas[3]  = R21 * Y10;
    bas[4]  = R21 * Y1p1;
    bas[5]  = R30 * Y00;
    bas[6]  = R31 * Y1m1;
    bas[7]  = R31 * Y10;
    bas[8]  = R31 * Y1p1;
    bas[9]  = R32 * Y2m2;
    bas[10] = R32 * Y2m1;
    bas[11] = R32 * Y20;
    bas[12] = R32 * Y2p1;
    bas[13] = R32 * Y2p2;
    bas[14] = R40 * Y00;
    bas[15] = R41 * Y1m1;
    bas[16] = R41 * Y10;
    bas[17] = R41 * Y1p1;
    bas[18] = R42 * Y2m2;
    bas[19] = R42 * Y2m1;
    bas[20] = R42 * Y20;
    bas[21] = R42 * Y2p1;
    bas[22] = R42 * Y2p2;
    bas[23] = R43 * Y3m3;
    bas[24] = R43 * Y3m2;
    bas[25] = R43 * Y3m1;
    bas[26] = R43 * Y30;
    bas[27] = R43 * Y3p1;
    bas[28] = R43 * Y3p2;
    bas[29] = R43 * Y3p3;
}

// 4 consecutive points per thread -> float4 stores (1 KB per wave-instr,
// the same write shape the 6.9 TB/s fill kernel uses). No LDS, no barriers.
__global__ __launch_bounds__(256, 3)
void dcconv_basis_gemm(const float* __restrict__ pos,     // (NPTS, 3)
                       const float* __restrict__ coeffs,  // (NOI, NB)
                       float* __restrict__ out)           // (NOI, NPTS)
{
    const int quad = blockIdx.x * 256 + threadIdx.x;  // 0..NQUAD-1, grid exact
    const int p0   = quad * 4;
    const int oi0  = blockIdx.y * OI_CHUNK;

    // basis for 4 consecutive points, fully register-resident (120 VGPR)
    float bas[4][NB];
    #pragma unroll
    for (int q = 0; q < 4; ++q) {
        const float r     = pos[(p0 + q) * 3 + 0];
        const float theta = pos[(p0 + q) * 3 + 1];
        const float phi   = pos[(p0 + q) * 3 + 2];
        eval_basis(r, theta, phi, bas[q]);
    }

    // einsum slice: out[oi][p0..p0+3] = coeffs[oi] . bas[:][:]
    // coeffs is wave-uniform -> s_loads; store is float4, lane-contiguous.
    float4* outq = reinterpret_cast<float4*>(out) + quad;
    for (int k = 0; k < OI_CHUNK; ++k) {
        const float* cf = coeffs + (size_t)(oi0 + k) * NB;
        float a0 = 0.0f, a1 = 0.0f, a2 = 0.0f, a3 = 0.0f;
        #pragma unroll
        for (int b = 0; b < NB; ++b) {
            const float c = cf[b];
            a0 = fmaf(c, bas[0][b], a0);
            a1 = fmaf(c, bas[1][b], a1);
            a2 = fmaf(c, bas[2][b], a2);
            a3 = fmaf(c, bas[3][b], a3);
        }
        outq[(size_t)(oi0 + k) * (NPTS / 4)] = make_float4(a0, a1, a2, a3);
    }
}

extern "C" void kernel_launch(void* const* d_in, const int* in_sizes, int n_in,
                              void* d_out, int out_size, void* d_ws, size_t ws_size,
                              hipStream_t stream) {
    const float* pos    = (const float*)d_in[0];  // (4096, 27, 3)
    const float* coeffs = (const float*)d_in[1];  // (16, 16, 30)
    float* out = (float*)d_out;                   // (16, 16, 4096, 27)

    dim3 grid(NQUAD / 256, NCHUNK);  // 108 x 8
    dim3 block(256);
    dcconv_basis_gemm<<<grid, block, 0, stream>>>(pos, coeffs, out);
}

// Round 6
// 32.173 us; speedup vs baseline: 10.8169x; 10.8169x over previous
//
#include <hip/hip_runtime.h>
#include <math.h>

#define OUTN  4096
#define CONVN 27
#define NPTS  (OUTN * CONVN)     // 110592
#define NPAIR (NPTS / 2)         // 55296 = 216 * 256 point-pairs
#define NB    30
#define NOI   256                // OUTC * INC
#define OI_CHUNK 32              // oi per block
#define NCHUNK (NOI / OI_CHUNK)  // 8

typedef float floatx2 __attribute__((ext_vector_type(2)));  // native vector for nontemporal builtin

// Evaluate the 30 hydrogen-wavefunction basis values for one point.
__device__ __forceinline__ void eval_basis(float r, float theta, float phi,
                                           float* __restrict__ bas)
{
    // ---- angular pieces ----
    const float ct = cosf(theta);
    const float st = sqrtf(fmaxf(1.0f - ct * ct, 0.0f));  // matches ref clip
    float s1, c1;
    sincosf(phi, &s1, &c1);
    const float c2 = c1 * c1 - s1 * s1;
    const float s2 = 2.0f * c1 * s1;
    const float c3 = c2 * c1 - s2 * s1;
    const float s3 = s2 * c1 + c2 * s1;

    // Associated Legendre with Condon–Shortley phase (matches ref _plm)
    const float P11 = -st;
    const float P20 = 0.5f * (3.0f * ct * ct - 1.0f);
    const float P21 = -3.0f * ct * st;
    const float P22 = 3.0f * (1.0f - ct * ct);
    const float P30 = 0.5f * ct * (5.0f * ct * ct - 3.0f);
    const float P31 = -1.5f * (5.0f * ct * ct - 1.0f) * st;
    const float P32 = 15.0f * ct * (1.0f - ct * ct);
    const float P33 = -15.0f * st * st * st;

    // Y_lm normalization constants (sqrtf of literals -> constant-folded)
    const float PI   = 3.14159265358979323846f;
    const float K00  = sqrtf(1.0f / (4.0f * PI));
    const float K10  = sqrtf(3.0f / (4.0f * PI));
    const float SK11 = sqrtf(2.0f) * sqrtf(3.0f / (8.0f * PI));
    const float K20  = sqrtf(5.0f / (4.0f * PI));
    const float SK21 = sqrtf(2.0f) * sqrtf(5.0f / (24.0f * PI));
    const float SK22 = sqrtf(2.0f) * sqrtf(5.0f / (96.0f * PI));
    const float K30  = sqrtf(7.0f / (4.0f * PI));
    const float SK31 = sqrtf(2.0f) * sqrtf(7.0f / (48.0f * PI));
    const float SK32 = sqrtf(2.0f) * sqrtf(7.0f / (480.0f * PI));
    const float SK33 = sqrtf(2.0f) * sqrtf(7.0f / (2880.0f * PI));

    const float Y00  = K00;
    const float Y1m1 = SK11 * P11 * s1;
    const float Y10  = K10 * ct;
    const float Y1p1 = SK11 * P11 * c1;
    const float Y2m2 = SK22 * P22 * s2;
    const float Y2m1 = SK21 * P21 * s1;
    const float Y20  = K20 * P20;
    const float Y2p1 = SK21 * P21 * c1;
    const float Y2p2 = SK22 * P22 * c2;
    const float Y3m3 = SK33 * P33 * s3;
    const float Y3m2 = SK32 * P32 * s2;
    const float Y3m1 = SK31 * P31 * s1;
    const float Y30  = K30 * P30;
    const float Y3p1 = SK31 * P31 * c1;
    const float Y3p2 = SK32 * P32 * c2;
    const float Y3p3 = SK33 * P33 * c3;

    // ---- radial parts R_nl(r), Bohr radius 1, rho = 2r/n ----
    const float e1 = expf(-r);                 // n=1
    const float e2 = expf(-0.5f * r);          // n=2
    const float e3 = expf(-r * (1.0f / 3.0f)); // n=3
    const float e4 = expf(-0.25f * r);         // n=4
    const float q2 = r;
    const float q3 = (2.0f / 3.0f) * r;
    const float q4 = 0.5f * r;

    const float R10 = 2.0f * e1;
    const float R20 = sqrtf(1.0f / 8.0f)       * e2 * (2.0f - q2);
    const float R21 = sqrtf(1.0f / 24.0f)      * e2 * q2;
    const float R30 = sqrtf(8.0f / 486.0f)     * e3 * (3.0f - 3.0f * q3 + 0.5f * q3 * q3);
    const float R31 = sqrtf(8.0f / 3888.0f)    * e3 * q3 * (4.0f - q3);
    const float R32 = sqrtf(8.0f / 19440.0f)   * e3 * q3 * q3;
    const float R40 = 0.0625f                  * e4 * (4.0f - 6.0f * q4 + 2.0f * q4 * q4 - q4 * q4 * q4 * (1.0f / 6.0f));
    const float R41 = sqrtf(0.25f / 960.0f)    * e4 * q4 * (10.0f - 5.0f * q4 + 0.5f * q4 * q4);
    const float R42 = sqrtf(0.125f / 5760.0f)  * e4 * q4 * q4 * (6.0f - q4);
    const float R43 = sqrtf(0.125f / 40320.0f) * e4 * q4 * q4 * q4;

    // ---- basis in QNUMS order ----
    bas[0]  = R10 * Y00;
    bas[1]  = R20 * Y00;
    bas[2]  = R21 * Y1m1;
    bas[3]  = R21 * Y10;
    bas[4]  = R21 * Y1p1;
    bas[5]  = R30 * Y00;
    bas[6]  = R31 * Y1m1;
    bas[7]  = R31 * Y10;
    bas[8]  = R31 * Y1p1;
    bas[9]  = R32 * Y2m2;
    bas[10] = R32 * Y2m1;
    bas[11] = R32 * Y20;
    bas[12] = R32 * Y2p1;
    bas[13] = R32 * Y2p2;
    bas[14] = R40 * Y00;
    bas[15] = R41 * Y1m1;
    bas[16] = R41 * Y10;
    bas[17] = R41 * Y1p1;
    bas[18] = R42 * Y2m2;
    bas[19] = R42 * Y2m1;
    bas[20] = R42 * Y20;
    bas[21] = R42 * Y2p1;
    bas[22] = R42 * Y2p2;
    bas[23] = R43 * Y3m3;
    bas[24] = R43 * Y3m2;
    bas[25] = R43 * Y3m1;
    bas[26] = R43 * Y30;
    bas[27] = R43 * Y3p1;
    bas[28] = R43 * Y3p2;
    bas[29] = R43 * Y3p3;
}

// 2 consecutive points per thread -> dwordx2 stores (512 B per wave-instr).
// bas[2][30] = 60 floats stays register-resident (the 4-point variant spilled
// at 120 floats: round-4 FETCH_SIZE 528 MB). No LDS, no barriers, no
// launch_bounds min-waves cap (capping registers is what forced the spill).
__global__ __launch_bounds__(256)
void dcconv_basis_gemm(const float* __restrict__ pos,     // (NPTS, 3)
                       const float* __restrict__ coeffs,  // (NOI, NB)
                       float* __restrict__ out)           // (NOI, NPTS)
{
    const int pair = blockIdx.x * 256 + threadIdx.x;  // 0..NPAIR-1, grid exact
    const int p0   = pair * 2;
    const int oi0  = blockIdx.y * OI_CHUNK;

    float bas[2][NB];
    #pragma unroll
    for (int q = 0; q < 2; ++q) {
        const float r     = pos[(p0 + q) * 3 + 0];
        const float theta = pos[(p0 + q) * 3 + 1];
        const float phi   = pos[(p0 + q) * 3 + 2];
        eval_basis(r, theta, phi, bas[q]);
    }

    // einsum slice: out[oi][p0..p0+1] = coeffs[oi] . bas[:][:]
    // coeffs is wave-uniform -> s_loads; store is dwordx2, lane-contiguous.
    floatx2* outp = reinterpret_cast<floatx2*>(out) + pair;
    #pragma unroll 4
    for (int k = 0; k < OI_CHUNK; ++k) {
        const float* cf = coeffs + (size_t)(oi0 + k) * NB;
        float a0 = 0.0f, a1 = 0.0f;
        #pragma unroll
        for (int b = 0; b < NB; ++b) {
            const float c = cf[b];
            a0 = fmaf(c, bas[0][b], a0);
            a1 = fmaf(c, bas[1][b], a1);
        }
        floatx2 v; v.x = a0; v.y = a1;
        __builtin_nontemporal_store(v, &outp[(size_t)(oi0 + k) * (NPTS / 2)]);
    }
}

extern "C" void kernel_launch(void* const* d_in, const int* in_sizes, int n_in,
                              void* d_out, int out_size, void* d_ws, size_t ws_size,
                              hipStream_t stream) {
    const float* pos    = (const float*)d_in[0];  // (4096, 27, 3)
    const float* coeffs = (const float*)d_in[1];  // (16, 16, 30)
    float* out = (float*)d_out;                   // (16, 16, 4096, 27)

    dim3 grid(NPAIR / 256, NCHUNK);  // 216 x 8
    dim3 block(256);
    dcconv_basis_gemm<<<grid, block, 0, stream>>>(pos, coeffs, out);
}